// Round 18
// baseline (99.040 us; speedup 1.0000x reference)
//
#include <hip/hip_runtime.h>

// 19x19 box-sum, reflect pad 9, input (16,3,1024,1024) f32.
// V18 = V8 (last plain-HIP kernel that ran: 93.7us, zero inline asm,
// wave-autonomous streaming, register pipeline+ring, DPP wave-prefix
// horizontal with 1-ahead staging, XCD swizzle) + the queued experiment:
//   YSEG 128 -> 64: 3072 blocks (12/CU, 48 waves/CU demand vs 32-slot cap)
//   -> saturated SIMD slots. V8 measured occ 43%, VALUBusy 47%, BW 3.5TB/s
//   (TLP-starved; compiler sinks prefetch to ~4-deep regardless of hints).
// The V9-V17 asm-pinned line is abandoned: 5 of 7 asm variants crashed the
// compiler (ISel/regalloc aborts on the "s"-constrained soffset shapes);
// plain loads compile robustly and cost only ~5% vs asm (93.7 vs 88.7).
// Loop restructure is trip-count-only vs V8: main = 3 chunks of 19 + 6-step
// remainder (same j-sequencing a 4th chunk would have), single staged finish.

#define H    1024
#define W    1024
#define RAD  9
#define KW   19
#define YSEG 64
#define NT   256          // 4 independent waves per block, no barriers

__device__ __forceinline__ int reflecti(int i, int n) {
    i = (i < 0) ? -i : i;
    return (i > n - 1) ? (2 * (n - 1) - i) : i;
}

// s + dpp(s); old=0, bound_ctrl=1 -> out-of-range/unselected rows add 0.
template<int CTRL, int RMASK>
__device__ __forceinline__ float dpp_add(float s) {
    int t = __builtin_amdgcn_update_dpp(0, __float_as_int(s), CTRL, RMASK, 0xf, true);
    return s + __int_as_float(t);
}

// wave64 inclusive prefix sum (4x row_shr + 2x row_bcast) — HW-verified V5-V10
__device__ __forceinline__ float wave_prefix_incl(float x) {
    x = dpp_add<0x111, 0xf>(x);   // row_shr:1
    x = dpp_add<0x112, 0xf>(x);   // row_shr:2
    x = dpp_add<0x114, 0xf>(x);   // row_shr:4
    x = dpp_add<0x118, 0xf>(x);   // row_shr:8
    x = dpp_add<0x142, 0xa>(x);   // row_bcast:15 -> rows 1,3
    x = dpp_add<0x143, 0xc>(x);   // row_bcast:31 -> rows 2,3
    return x;
}

__global__ __launch_bounds__(NT, 4)
void boxsum19_kernel(const float* __restrict__ in, float* __restrict__ out) {
    const int lane = threadIdx.x & 63;
    const int wid  = threadIdx.x >> 6;

    // XCD-chunked bijective swizzle: 3072 blocks = 8 XCDs x 384 (6 images ea.)
    const int flat = blockIdx.x;
    const int wg   = (flat & 7) * 384 + (flat >> 3);
    const int img  = wg >> 6;            // 0..47  (64 blocks per image)
    const int rem  = wg & 63;
    const int by   = rem >> 4;           // 0..3   (y quarter)
    const int strip = rem & 15;          // 0..15  (64-col strips)

    const int x0  = strip * 64;
    const int y0r = __builtin_amdgcn_readfirstlane((by * 4 + wid) * YSEG);
    const size_t img_off = (size_t)img * (size_t)(H * W);
    const float* __restrict__ inp  = in  + img_off;
    float* __restrict__       outp = out + img_off;

    // Row segment s[j] = x_reflect[x0-16+j]: a = j 0..63, b = j 64..88
    // (only Pb lanes 0..24 consumed by the splice). Reflect folded in.
    const int gxa = reflecti(x0 - 16 + lane, W);
    const int gxb = reflecti(x0 + 48 + lane, W);
    const bool ld_b = (lane < 25);
    // h[k] = P[k+25] - P[k+6] (19-tap around col x0+k), P = spliced prefix.
    const int  i6   = ((lane + 6)  & 63) << 2;   // bpermute byte index
    const int  i25  = ((lane + 25) & 63) << 2;
    const bool c6   = lane < 6;    // merged-source: src[m] = m<6  ? Pb : Pa
    const bool c25  = lane < 25;   // merged-source: src[m] = m<25 ? Pb : Pa
    const int  outcol = x0 + lane;

    float ea[KW], eb[KW], ring[KW];
    float vsum = 0.f;

#define LOADROW(trow, slot) do {                                         \
        const int gy_ = reflecti(y0r - RAD + (trow), H);                 \
        const float* rp_ = inp + ((size_t)gy_ << 10);                    \
        ea[slot] = rp_[gxa];                                             \
        if (ld_b) eb[slot] = rp_[gxb];                                   \
    } while (0)

// issue the horizontal chain for a row: prefix + splice + 2 bpermutes.
// q/r are consumed by the NEXT step (h = r - q) -> latency overlapped.
#define HSTART(slot, q, r) do {                                          \
        float Pa_ = wave_prefix_incl(ea[slot]);                          \
        float Pb_ = wave_prefix_incl(eb[slot]);                          \
        const float At_ = __int_as_float(                                \
            __builtin_amdgcn_readlane(__float_as_int(Pa_), 63));         \
        Pb_ += At_;                                                      \
        const float mq_ = c6  ? Pb_ : Pa_;                               \
        const float mr_ = c25 ? Pb_ : Pa_;                               \
        q = __int_as_float(                                              \
            __builtin_amdgcn_ds_bpermute(i6,  __float_as_int(mq_)));     \
        r = __int_as_float(                                              \
            __builtin_amdgcn_ds_bpermute(i25, __float_as_int(mr_)));     \
    } while (0)

    // init eb so masked lanes hold a defined value (never consumed anyway)
    #pragma unroll
    for (int j = 0; j < KW; ++j) eb[j] = 0.f;

    // ---- initial loads: rows 0..18 into slots 0..18 ----
    #pragma unroll
    for (int j = 0; j < KW; ++j) LOADROW(j, j);

    // ---- fill: rows 0..17 -> ring/vsum; prefetch rows 19..36 ----
    #pragma unroll
    for (int j = 0; j < KW - 1; ++j) {
        float q_, r_; HSTART(j, q_, r_);
        const float h = r_ - q_;
        LOADROW(j + KW, j);          // after consume: anti-dep keeps order
        ring[j] = h;
        vsum += h;
    }

    float qc, rc;
    HSTART(18, qc, rc);              // stage row 18 (slot 18)

    // ---- main: t=18..74 (3 chunks of 19) + t=75..80 (remainder) ----
    // outputs 0..62; each step finishes row t, stages row t+1, loads t+19.
    int t = KW - 1;
    for (int blk = 0; blk < 3; ++blk) {
        #pragma unroll
        for (int j = 0; j < KW; ++j) {
            const int slot = (KW - 1 + j) % KW;
            const float h = rc - qc;     // finish row t (staged last step)
            HSTART(j, qc, rc);           // stage row t+1 (slot j)
            LOADROW(t + KW, slot);       // prefetch row t+19 into freed slot
            vsum += h;
            outp[(size_t)(y0r + t - (KW - 1)) * W + outcol] = vsum;
            vsum -= ring[j];
            ring[slot] = h;
            ++t;
        }
    }
    #pragma unroll
    for (int j = 0; j < 6; ++j) {        // t = 75..80 (4th chunk, truncated)
        const int slot = (KW - 1 + j) % KW;
        const float h = rc - qc;
        HSTART(j, qc, rc);               // stages rows 76..81
        LOADROW(t + KW, slot);           // rows 94..99 (reflected; cache-hot)
        vsum += h;
        outp[(size_t)(y0r + t - (KW - 1)) * W + outcol] = vsum;
        vsum -= ring[j];
        ring[slot] = h;
        ++t;
    }

    // ---- epilogue: finish row 81 -> output 63 ----
    {
        const float h = rc - qc;
        vsum += h;
        outp[(size_t)(y0r + YSEG - 1) * W + outcol] = vsum;
    }

#undef LOADROW
#undef HSTART
}

extern "C" void kernel_launch(void* const* d_in, const int* in_sizes, int n_in,
                              void* d_out, int out_size, void* d_ws, size_t ws_size,
                              hipStream_t stream) {
    const float* in = (const float*)d_in[0];
    float* out = (float*)d_out;
    dim3 grid(16 * 4 * 48, 1, 1);   // 3072 blocks (4 waves each), XCD-swizzled
    boxsum19_kernel<<<grid, NT, 0, stream>>>(in, out);
}